// Round 13
// baseline (4122.651 us; speedup 1.0000x reference)
//
#include <hip/hip_runtime.h>
#include <hip/hip_bf16.h>

#define HH 51
#define TPB 1024    // 16 waves; P1: wave=batch; P2: waves 0-2 = one matrix each
#define BPB 16      // full MFMA M dimension; grid 128
#define GMS 17      // gbuf row stride (floats), odd -> <=2-way banks

typedef _Float16 half8 __attribute__((ext_vector_type(8)));
typedef float f4 __attribute__((ext_vector_type(4)));

__device__ __forceinline__ float bf2f(unsigned short u) {
    return __uint_as_float(((unsigned)u) << 16);
}
__device__ __forceinline__ float loadf(const void* p, size_t i, bool bf) {
    return bf ? bf2f(((const unsigned short*)p)[i]) : ((const float*)p)[i];
}
__device__ __forceinline__ void storef(void* p, size_t i, float v, bool bf) {
    if (bf) ((__hip_bfloat16*)p)[i] = __float2bfloat16(v);
    else    ((float*)p)[i] = v;
}
__device__ __forceinline__ float sigm(float v) {
    float e = __expf(-fabsf(v));
    float s = 1.0f / (1.0f + e);
    return (v >= 0.0f) ? s : 1.0f - s;
}
__device__ __forceinline__ float tanh_fast(float v) {
    float e = __expf(-2.0f * fabsf(v));
    float t = (1.0f - e) / (1.0f + e);
    return (v >= 0.0f) ? t : -t;
}
__device__ __forceinline__ f4 MF(half8 a, half8 b, f4 c) {
    return __builtin_amdgcn_mfma_f32_16x16x32_f16(a, b, c, 0, 0, 0);
}
// wave64 sum via DPP (verified rounds 5-11), result uniform across lanes
__device__ __forceinline__ float wave_sum(float x) {
    float s = x, t;
    t = __builtin_bit_cast(float, __builtin_amdgcn_update_dpp(0, __builtin_bit_cast(int, s), 0x111, 0xf, 0xf, true)); s += t;
    t = __builtin_bit_cast(float, __builtin_amdgcn_update_dpp(0, __builtin_bit_cast(int, s), 0x112, 0xf, 0xf, true)); s += t;
    t = __builtin_bit_cast(float, __builtin_amdgcn_update_dpp(0, __builtin_bit_cast(int, s), 0x114, 0xf, 0xf, true)); s += t;
    t = __builtin_bit_cast(float, __builtin_amdgcn_update_dpp(0, __builtin_bit_cast(int, s), 0x118, 0xf, 0xf, true)); s += t;
    t = __builtin_bit_cast(float, __builtin_amdgcn_update_dpp(0, __builtin_bit_cast(int, s), 0x142, 0xa, 0xf, true)); s += t;
    t = __builtin_bit_cast(float, __builtin_amdgcn_update_dpp(0, __builtin_bit_cast(int, s), 0x143, 0xc, 0xf, true)); s += t;
    return __builtin_bit_cast(float, __builtin_amdgcn_readlane(__builtin_bit_cast(int, s), 63));
}

__global__ __launch_bounds__(TPB, 1) void gru_kernel(
    const void* __restrict__ xg,
    const void* __restrict__ wih1, const void* __restrict__ whh1,
    const void* __restrict__ bih1, const void* __restrict__ bhh1,
    const void* __restrict__ wih2, const void* __restrict__ whh2,
    const void* __restrict__ bih2, const void* __restrict__ bhh2,
    const void* __restrict__ wlin, const void* __restrict__ blin_p,
    void* __restrict__ dout, int T, int TF)
{
    __shared__ __align__(16) _Float16 stg[160 * 64];          // 20480 B
    __shared__ __align__(16) float    gbuf[3 * 160 * GMS];    // 32640 B
    __shared__ __align__(16) _Float16 h1hi[16 * 72];          // 16 batch rows
    __shared__ __align__(16) _Float16 h1lo[16 * 72];
    __shared__ __align__(16) _Float16 h2hi[16 * 72];
    __shared__ __align__(16) _Float16 h2lo[16 * 72];
    __shared__ float obufL[BPB * 36];                          // 2304 B

    const int tid = threadIdx.x, w = tid >> 6, lane = tid & 63;
    const int n16 = lane & 15, quad = lane >> 4;
    const bool li = lane < HH;
    const int il = li ? lane : HH - 1;
    const int bg0 = blockIdx.x * BPB;
    const int myb = bg0 + w;         // each of the 16 waves owns one batch

    // runtime dtype detection (fp32 vs bf16), uniform
    bool isbf;
    {
        const unsigned short* u = (const unsigned short*)whh1;
        int ok = 1;
#pragma unroll
        for (int k = 0; k < 16; ++k) {
            unsigned e = (u[2 * k] >> 7) & 0xFF;
            ok &= (e >= 100 && e <= 125) ? 1 : 0;
        }
        isbf = (ok != 0);
    }

    // ---- stage matrices (f16, bias folded at k=52); wave w<3 snapshots matrix w ----
    half8 W[10][2];
#pragma unroll 1
    for (int mt = 0; mt < 3; ++mt) {
        const void* wm = (mt == 0) ? whh1 : (mt == 1) ? whh2 : wih2;
        for (int e = tid; e < 160 * 64; e += TPB) {
            int g = e >> 6, k = e & 63;
            float v = 0.0f;
            if (g < 3 * HH) {
                if (k < HH) v = loadf(wm, (size_t)g * HH + k, isbf);
                else if (k == 52) {
                    if (mt == 0)      v = loadf(bhh1, g, isbf) + ((g < 2 * HH) ? loadf(bih1, g, isbf) : 0.0f);
                    else if (mt == 1) v = loadf(bhh2, g, isbf);
                    else              v = loadf(bih2, g, isbf);
                }
            }
            stg[e] = (_Float16)v;
        }
        __syncthreads();
        if (w == mt) {
#pragma unroll
            for (int tl = 0; tl < 10; ++tl) {
                W[tl][0] = *(const half8*)(stg + (size_t)(16 * tl + n16) * 64 + quad * 8);
                W[tl][1] = *(const half8*)(stg + (size_t)(16 * tl + n16) * 64 + 32 + quad * 8);
            }
        }
        __syncthreads();
    }

    // ---- init runtime LDS ----
    for (int e = tid; e < 1152; e += TPB) { h1hi[e] = (_Float16)0; h1lo[e] = (_Float16)0;
                                            h2hi[e] = (_Float16)0; h2lo[e] = (_Float16)0; }
    for (int e = tid; e < 3 * 160 * GMS; e += TPB) gbuf[e] = 0.0f;

    // elementwise constants (lane = hidden unit)
    float wr1 = 0, wz1 = 0, wn1 = 0, bn1 = 0, wl = 0;
    if (li) {
        wr1 = loadf(wih1, il, isbf);          wz1 = loadf(wih1, HH + il, isbf);
        wn1 = loadf(wih1, 2 * HH + il, isbf); bn1 = loadf(bih1, 2 * HH + il, isbf);
        wl  = loadf(wlin, il, isbf);
    }
    const float blv = loadf(blin_p, 0, isbf);

    // x prefetch: lane l holds x[myb][t0 + l], 64 steps per reload
    float xreg = 0.0f;
    if (lane < T) xreg = loadf(xg, (size_t)myb * T + lane, isbf);
    __syncthreads();
    if (tid < BPB) { h1hi[tid * 72 + 52] = (_Float16)1.0f; h2hi[tid * 72 + 52] = (_Float16)1.0f; }
    __syncthreads();

    // ---- prologue: wave0 computes gh1(0) from bias-slot h1 ----
    if (w == 0) {
        half8 Ah0 = *(const half8*)(h1hi + n16 * 72 + quad * 8);
        half8 Ah1 = *(const half8*)(h1hi + n16 * 72 + 32 + quad * 8);
        half8 Al0 = *(const half8*)(h1lo + n16 * 72 + quad * 8);
        half8 Al1 = *(const half8*)(h1lo + n16 * 72 + 32 + quad * 8);
#pragma unroll
        for (int tl = 0; tl < 10; ++tl) {
            f4 acc = {0.f, 0.f, 0.f, 0.f};
            acc = MF(Ah0, W[tl][0], acc); acc = MF(Ah1, W[tl][1], acc);
            acc = MF(Al0, W[tl][0], acc); acc = MF(Al1, W[tl][1], acc);
            // C layout: col=n16 (gate row), row=quad*4+reg (batch) -> ALL quads stored
            *(f4*)(gbuf + (16 * tl + n16) * GMS + quad * 4) = acc;
        }
    }
    __syncthreads();

    float h1p = 0.0f, h2p = 0.0f, outv = 0.0f;
    const int base1 = 160 * GMS, base2 = 320 * GMS;

    for (int t = 0; t < TF; ++t) {
        // ======== P1: all 16 waves elementwise, batch = w ========
        float g1r = gbuf[il * GMS + w];
        float g1z = gbuf[(HH + il) * GMS + w];
        float g1n = gbuf[(2 * HH + il) * GMS + w];
        float p = 0.0f;
        if (t > 0) {   // e2(t-1)
            float ghr = gbuf[base1 + il * GMS + w], ghz = gbuf[base1 + (HH + il) * GMS + w], ghn = gbuf[base1 + (2 * HH + il) * GMS + w];
            float gir = gbuf[base2 + il * GMS + w], giz = gbuf[base2 + (HH + il) * GMS + w], gin = gbuf[base2 + (2 * HH + il) * GMS + w];
            float r2 = sigm(gir + ghr), z2 = sigm(giz + ghz);
            float n2 = tanh_fast(gin + r2 * ghn);
            float h = n2 + z2 * (h2p - n2); h2p = h;
            if (li) {
                _Float16 hi = (_Float16)h;
                h2hi[w * 72 + il] = hi; h2lo[w * 72 + il] = (_Float16)(h - (float)hi);
                p = h * wl;
            }
        }
        float osum = wave_sum(p) + blv;
        if (t > 0) {
            outv = osum;
            if (lane == 0) obufL[w * 36 + ((t - 1) & 31)] = outv;
        }
        float xv = (t < T) ? __builtin_bit_cast(float, __builtin_amdgcn_readlane(__builtin_bit_cast(int, xreg), t & 63))
                           : outv;
        {   // e1(t)
            float r = sigm(fmaf(xv, wr1, g1r));
            float z = sigm(fmaf(xv, wz1, g1z));
            float n = tanh_fast(fmaf(xv, wn1, bn1) + r * g1n);
            float h = n + z * (h1p - n); h1p = h;
            if (li) {
                _Float16 hi = (_Float16)h;
                h1hi[w * 72 + il] = hi; h1lo[w * 72 + il] = (_Float16)(h - (float)hi);
            }
        }
        __syncthreads();

        // ======== P2: waves 0-2 matmul (one matrix each); waves 3-10 flush ========
        if (w < 3) {
            // wave0: gh1(t+1)=h1@Whh1 ; wave1: gh2(t)=h2@Whh2 ; wave2: gi2(t)=h1@Wih2
            const _Float16* ah = (w == 1) ? h2hi : h1hi;
            const _Float16* al = (w == 1) ? h2lo : h1lo;
            half8 Ah0 = *(const half8*)(ah + n16 * 72 + quad * 8);
            half8 Ah1 = *(const half8*)(ah + n16 * 72 + 32 + quad * 8);
            half8 Al0 = *(const half8*)(al + n16 * 72 + quad * 8);
            half8 Al1 = *(const half8*)(al + n16 * 72 + 32 + quad * 8);
            float* dst = gbuf + w * 160 * GMS;
#pragma unroll
            for (int tl = 0; tl < 10; ++tl) {
                f4 acc = {0.f, 0.f, 0.f, 0.f};
                acc = MF(Ah0, W[tl][0], acc); acc = MF(Ah1, W[tl][1], acc);
                acc = MF(Al0, W[tl][0], acc); acc = MF(Al1, W[tl][1], acc);
                // ALL quads stored: batches 0-15 live in rows quad*4+reg
                *(f4*)(dst + (16 * tl + n16) * GMS + quad * 4) = acc;
            }
        } else if ((t & 31) == 0 && t > 0) {
            int et = (w - 3) * 64 + lane;
            if (et < BPB * 32) {
                int b = et >> 5, tt = et & 31;
                storef(dout, (size_t)(bg0 + b) * TF + (t - 32) + tt, obufL[b * 36 + tt], isbf);
            }
        }
        if ((t & 63) == 63 && (t + 1) < T) {   // x reload for [t+1, t+64]
            int src = t + 1 + lane;
            xreg = (src < T) ? loadf(xg, (size_t)myb * T + src, isbf) : 0.0f;
        }
        __syncthreads();
    }

    // ---- epilogue: e2(TF-1) + out(TF-1) + tail flush ----
    {
        float ghr = gbuf[base1 + il * GMS + w], ghz = gbuf[base1 + (HH + il) * GMS + w], ghn = gbuf[base1 + (2 * HH + il) * GMS + w];
        float gir = gbuf[base2 + il * GMS + w], giz = gbuf[base2 + (HH + il) * GMS + w], gin = gbuf[base2 + (2 * HH + il) * GMS + w];
        float p = 0.0f;
        float r2 = sigm(gir + ghr), z2 = sigm(giz + ghz);
        float n2 = tanh_fast(gin + r2 * ghn);
        float h = n2 + z2 * (h2p - n2);
        if (li) p = h * wl;
        float osum = wave_sum(p) + blv;
        if (lane == 0) obufL[w * 36 + ((TF - 1) & 31)] = osum;
    }
    __syncthreads();
    {
        int base = (TF - 1) & ~31, rem = TF - base;
        if (tid < BPB * 32) {
            int b = tid >> 5, tt = tid & 31;
            if (tt < rem)
                storef(dout, (size_t)(bg0 + b) * TF + base + tt, obufL[b * 36 + tt], isbf);
        }
    }
}

extern "C" void kernel_launch(void* const* d_in, const int* in_sizes, int n_in,
                              void* d_out, int out_size, void* d_ws, size_t ws_size,
                              hipStream_t stream) {
    const int B = 2048;
    const int T = in_sizes[0] / B;   // 1000
    const int TF = out_size / B;     // 2000
    gru_kernel<<<dim3(B / BPB), dim3(TPB), 0, stream>>>(
        d_in[0], d_in[1], d_in[2], d_in[3], d_in[4], d_in[5],
        d_in[6], d_in[7], d_in[8], d_in[9], d_in[10],
        d_out, T, TF);
}

// Round 14
// 2630.943 us; speedup vs baseline: 1.5670x; 1.5670x over previous
//
#include <hip/hip_runtime.h>
#include <hip/hip_bf16.h>

#define HH 51
#define TPB 512     // 8 waves; P1: wave=batch; P2: waves 0-2 = one matrix each
#define BPB 8
#define GMS 9       // gbuf row stride (floats): <=2-way banks

typedef _Float16 half8 __attribute__((ext_vector_type(8)));
typedef float f4 __attribute__((ext_vector_type(4)));

__device__ __forceinline__ float bf2f(unsigned short u) {
    return __uint_as_float(((unsigned)u) << 16);
}
__device__ __forceinline__ float loadf(const void* p, size_t i, bool bf) {
    return bf ? bf2f(((const unsigned short*)p)[i]) : ((const float*)p)[i];
}
__device__ __forceinline__ void storef(void* p, size_t i, float v, bool bf) {
    if (bf) ((__hip_bfloat16*)p)[i] = __float2bfloat16(v);
    else    ((float*)p)[i] = v;
}
__device__ __forceinline__ float sigm(float v) {
    float e = __expf(-fabsf(v));
    float s = 1.0f / (1.0f + e);
    return (v >= 0.0f) ? s : 1.0f - s;
}
__device__ __forceinline__ float tanh_fast(float v) {
    float e = __expf(-2.0f * fabsf(v));
    float t = (1.0f - e) / (1.0f + e);
    return (v >= 0.0f) ? t : -t;
}
__device__ __forceinline__ f4 MF(half8 a, half8 b, f4 c) {
    return __builtin_amdgcn_mfma_f32_16x16x32_f16(a, b, c, 0, 0, 0);
}
// wave64 sum via DPP (verified rounds 5-13), result uniform across lanes
__device__ __forceinline__ float wave_sum(float x) {
    float s = x, t;
    t = __builtin_bit_cast(float, __builtin_amdgcn_update_dpp(0, __builtin_bit_cast(int, s), 0x111, 0xf, 0xf, true)); s += t;
    t = __builtin_bit_cast(float, __builtin_amdgcn_update_dpp(0, __builtin_bit_cast(int, s), 0x112, 0xf, 0xf, true)); s += t;
    t = __builtin_bit_cast(float, __builtin_amdgcn_update_dpp(0, __builtin_bit_cast(int, s), 0x114, 0xf, 0xf, true)); s += t;
    t = __builtin_bit_cast(float, __builtin_amdgcn_update_dpp(0, __builtin_bit_cast(int, s), 0x118, 0xf, 0xf, true)); s += t;
    t = __builtin_bit_cast(float, __builtin_amdgcn_update_dpp(0, __builtin_bit_cast(int, s), 0x142, 0xa, 0xf, true)); s += t;
    t = __builtin_bit_cast(float, __builtin_amdgcn_update_dpp(0, __builtin_bit_cast(int, s), 0x143, 0xc, 0xf, true)); s += t;
    return __builtin_bit_cast(float, __builtin_amdgcn_readlane(__builtin_bit_cast(int, s), 63));
}

__global__ __launch_bounds__(TPB, 2) void gru_kernel(
    const void* __restrict__ xg,
    const void* __restrict__ wih1, const void* __restrict__ whh1,
    const void* __restrict__ bih1, const void* __restrict__ bhh1,
    const void* __restrict__ wih2, const void* __restrict__ whh2,
    const void* __restrict__ bih2, const void* __restrict__ bhh2,
    const void* __restrict__ wlin, const void* __restrict__ blin_p,
    void* __restrict__ dout, int T, int TF)
{
    __shared__ __align__(16) _Float16 stg[160 * 64];        // 20480 B
    __shared__ __align__(16) float    gbuf[3 * 160 * GMS];  // 17280 B
    __shared__ __align__(16) _Float16 h1b[16 * 72];         // f16 state (no lo)
    __shared__ __align__(16) _Float16 h2b[16 * 72];
    __shared__ float obufL[BPB * 36];

    const int tid = threadIdx.x, w = tid >> 6, lane = tid & 63;
    const int n16 = lane & 15, quad = lane >> 4;
    const bool li = lane < HH;
    const int il = li ? lane : HH - 1;
    const int bg0 = blockIdx.x * BPB;
    const int myb = bg0 + w;         // each of the 8 waves owns one batch

    // runtime dtype detection (fp32 vs bf16), uniform
    bool isbf;
    {
        const unsigned short* u = (const unsigned short*)whh1;
        int ok = 1;
#pragma unroll
        for (int k = 0; k < 16; ++k) {
            unsigned e = (u[2 * k] >> 7) & 0xFF;
            ok &= (e >= 100 && e <= 125) ? 1 : 0;
        }
        isbf = (ok != 0);
    }

    // ---- stage matrices (f16, bias folded at k=52); wave w<3 snapshots matrix w ----
    half8 W[10][2];
#pragma unroll 1
    for (int mt = 0; mt < 3; ++mt) {
        const void* wm = (mt == 0) ? whh1 : (mt == 1) ? whh2 : wih2;
        for (int e = tid; e < 160 * 64; e += TPB) {
            int g = e >> 6, k = e & 63;
            float v = 0.0f;
            if (g < 3 * HH) {
                if (k < HH) v = loadf(wm, (size_t)g * HH + k, isbf);
                else if (k == 52) {
                    if (mt == 0)      v = loadf(bhh1, g, isbf) + ((g < 2 * HH) ? loadf(bih1, g, isbf) : 0.0f);
                    else if (mt == 1) v = loadf(bhh2, g, isbf);
                    else              v = loadf(bih2, g, isbf);
                }
            }
            stg[e] = (_Float16)v;
        }
        __syncthreads();
        if (w == mt) {
#pragma unroll
            for (int tl = 0; tl < 10; ++tl) {
                W[tl][0] = *(const half8*)(stg + (size_t)(16 * tl + n16) * 64 + quad * 8);
                W[tl][1] = *(const half8*)(stg + (size_t)(16 * tl + n16) * 64 + 32 + quad * 8);
            }
        }
        __syncthreads();
    }

    // ---- init runtime LDS ----
    for (int e = tid; e < 1152; e += TPB) { h1b[e] = (_Float16)0; h2b[e] = (_Float16)0; }
    for (int e = tid; e < 3 * 160 * GMS; e += TPB) gbuf[e] = 0.0f;

    // elementwise constants (lane = hidden unit)
    float wr1 = 0, wz1 = 0, wn1 = 0, bn1 = 0, wl = 0;
    if (li) {
        wr1 = loadf(wih1, il, isbf);          wz1 = loadf(wih1, HH + il, isbf);
        wn1 = loadf(wih1, 2 * HH + il, isbf); bn1 = loadf(bih1, 2 * HH + il, isbf);
        wl  = loadf(wlin, il, isbf);
    }
    const float blv = loadf(blin_p, 0, isbf);

    // x prefetch, double-buffered: xreg = [t0..t0+63], xnext loaded 63 steps early
    float xreg = 0.0f, xnext = 0.0f;
    if (lane < T) xreg = loadf(xg, (size_t)myb * T + lane, isbf);
    __syncthreads();
    if (tid < BPB) { h1b[tid * 72 + 52] = (_Float16)1.0f; h2b[tid * 72 + 52] = (_Float16)1.0f; }
    __syncthreads();

    // ---- prologue: wave0 computes gh1(0) from bias-slot h1 ----
    if (w == 0) {
        half8 Ah0 = *(const half8*)(h1b + n16 * 72 + quad * 8);
        half8 Ah1 = *(const half8*)(h1b + n16 * 72 + 32 + quad * 8);
#pragma unroll
        for (int tl = 0; tl < 10; ++tl) {
            f4 acc = {0.f, 0.f, 0.f, 0.f};
            acc = MF(Ah0, W[tl][0], acc); acc = MF(Ah1, W[tl][1], acc);
            if (quad < 2) *(f4*)(gbuf + (16 * tl + n16) * GMS + quad * 4) = acc;
        }
    }
    __syncthreads();

    float h1p = 0.0f, h2p = 0.0f, outv = 0.0f;
    const int base1 = 160 * GMS, base2 = 320 * GMS;

    for (int t = 0; t < TF; ++t) {
        // ======== P1: all waves elementwise, batch = w ========
        float g1r = gbuf[il * GMS + w];
        float g1z = gbuf[(HH + il) * GMS + w];
        float g1n = gbuf[(2 * HH + il) * GMS + w];
        float p = 0.0f;
        if (t > 0) {   // e2(t-1)
            float ghr = gbuf[base1 + il * GMS + w], ghz = gbuf[base1 + (HH + il) * GMS + w], ghn = gbuf[base1 + (2 * HH + il) * GMS + w];
            float gir = gbuf[base2 + il * GMS + w], giz = gbuf[base2 + (HH + il) * GMS + w], gin = gbuf[base2 + (2 * HH + il) * GMS + w];
            float r2 = sigm(gir + ghr), z2 = sigm(giz + ghz);
            float n2 = tanh_fast(gin + r2 * ghn);
            float h = n2 + z2 * (h2p - n2); h2p = h;
            if (li) {
                h2b[w * 72 + il] = (_Float16)h;
                p = h * wl;
            }
        }
        float osum = wave_sum(p) + blv;
        if (t > 0) {
            outv = osum;
            if (lane == 0) obufL[w * 36 + ((t - 1) & 31)] = outv;
        }
        float xv = (t < T) ? __builtin_bit_cast(float, __builtin_amdgcn_readlane(__builtin_bit_cast(int, xreg), t & 63))
                           : outv;
        {   // e1(t)
            float r = sigm(fmaf(xv, wr1, g1r));
            float z = sigm(fmaf(xv, wz1, g1z));
            float n = tanh_fast(fmaf(xv, wn1, bn1) + r * g1n);
            float h = n + z * (h1p - n); h1p = h;
            if (li) h1b[w * 72 + il] = (_Float16)h;
        }
        __syncthreads();

        // ======== P2: waves 0-2 matmul (one matrix each); waves 3-7 flush ========
        if (w < 3) {
            // wave0: gh1(t+1)=h1@Whh1 ; wave1: gh2(t)=h2@Whh2 ; wave2: gi2(t)=h1@Wih2
            const _Float16* ah = (w == 1) ? h2b : h1b;
            half8 Ah0 = *(const half8*)(ah + n16 * 72 + quad * 8);
            half8 Ah1 = *(const half8*)(ah + n16 * 72 + 32 + quad * 8);
            float* dst = gbuf + w * 1440;
#pragma unroll
            for (int tl = 0; tl < 10; ++tl) {
                f4 acc = {0.f, 0.f, 0.f, 0.f};
                acc = MF(Ah0, W[tl][0], acc); acc = MF(Ah1, W[tl][1], acc);
                if (quad < 2) *(f4*)(dst + (16 * tl + n16) * GMS + quad * 4) = acc;
            }
        } else if ((t & 31) == 0 && t > 0) {
            int et = (w - 3) * 64 + lane;
            if (et < BPB * 32) {
                int b = et >> 5, tt = et & 31;
                storef(dout, (size_t)(bg0 + b) * TF + (t - 32) + tt, obufL[b * 36 + tt], isbf);
            }
        }
        // x double-buffer: issue next window's load 63 steps early; swap at window end
        if ((t & 63) == 0) {
            int base = ((t >> 6) + 1) << 6;
            if (base < T) {
                int src = base + lane;
                xnext = (src < T) ? loadf(xg, (size_t)myb * T + src, isbf) : 0.0f;
            }
        } else if ((t & 63) == 63) {
            xreg = xnext;
        }
        __syncthreads();
    }

    // ---- epilogue: e2(TF-1) + out(TF-1) + tail flush ----
    {
        float ghr = gbuf[base1 + il * GMS + w], ghz = gbuf[base1 + (HH + il) * GMS + w], ghn = gbuf[base1 + (2 * HH + il) * GMS + w];
        float gir = gbuf[base2 + il * GMS + w], giz = gbuf[base2 + (HH + il) * GMS + w], gin = gbuf[base2 + (2 * HH + il) * GMS + w];
        float p = 0.0f;
        float r2 = sigm(gir + ghr), z2 = sigm(giz + ghz);
        float n2 = tanh_fast(gin + r2 * ghn);
        float h = n2 + z2 * (h2p - n2);
        if (li) p = h * wl;
        float osum = wave_sum(p) + blv;
        if (lane == 0) obufL[w * 36 + ((TF - 1) & 31)] = osum;
    }
    __syncthreads();
    {
        int base = (TF - 1) & ~31, rem = TF - base;
        if (tid < BPB * 32) {
            int b = tid >> 5, tt = tid & 31;
            if (tt < rem)
                storef(dout, (size_t)(bg0 + b) * TF + base + tt, obufL[b * 36 + tt], isbf);
        }
    }
}

extern "C" void kernel_launch(void* const* d_in, const int* in_sizes, int n_in,
                              void* d_out, int out_size, void* d_ws, size_t ws_size,
                              hipStream_t stream) {
    const int B = 2048;
    const int T = in_sizes[0] / B;   // 1000
    const int TF = out_size / B;     // 2000
    gru_kernel<<<dim3(B / BPB), dim3(TPB), 0, stream>>>(
        d_in[0], d_in[1], d_in[2], d_in[3], d_in[4], d_in[5],
        d_in[6], d_in[7], d_in[8], d_in[9], d_in[10],
        d_out, T, TF);
}